// Round 12
// baseline (726.383 us; speedup 1.0000x reference)
//
#include <hip/hip_runtime.h>
#include <hip/hip_bf16.h>
#include <stdint.h>

#define B_ 2
#define S_ 1024
#define E_ 512
#define H_ 8
#define D_ 64
#define M_ 2048
#define V_ 32000
#define L_ 2

typedef __hip_bfloat16 bf16;
typedef __attribute__((ext_vector_type(8))) short short8;
typedef __attribute__((ext_vector_type(4))) float f32x4;
typedef __attribute__((ext_vector_type(16))) float f32x16;
typedef __attribute__((ext_vector_type(4))) unsigned int uint4v;

__device__ inline unsigned int pack2bf(float lo, float hi) {
    __hip_bfloat16 a = __float2bfloat16(lo), b = __float2bfloat16(hi);
    unsigned short ua = *(unsigned short*)&a, ub = *(unsigned short*)&b;
    return (unsigned int)ua | ((unsigned int)ub << 16);
}

// ---------------- numpy legacy RandomState (MT19937) ----------------
#define MT_N 624
#define MT_M 397
#define MT_UP   0x80000000u
#define MT_LOW  0x7fffffffu
#define MT_MAT  0x9908b0dfu

__device__ inline unsigned int mt_temper(unsigned int y) {
    y ^= y >> 11;
    y ^= (y << 7) & 0x9d2c5680u;
    y ^= (y << 15) & 0xefc60000u;
    y ^= y >> 18;
    return y;
}

// ---------------- prep: embed + f32->bf16 cvt + zero vsum ----------------
__global__ __launch_bounds__(256)
void prep_kernel(const int* __restrict__ targets, const float* __restrict__ table,
                 const float* __restrict__ pos, float* __restrict__ y,
                 const float* __restrict__ enc, bf16* __restrict__ encb,
                 float* __restrict__ vmbase) {
    int bid = blockIdx.x, t = threadIdx.x;
    if (bid < 2048) {
        int s = bid & (S_ - 1), b = bid >> 10;
        int id = (s == 0) ? 0 : targets[b * S_ + s - 1];
        int c = t * 2;
        float2 e = *(const float2*)&table[(size_t)id * E_ + c];
        float2 p = *(const float2*)&pos[(size_t)s * E_ + c];
        float2 o = {e.x + p.x, e.y + p.y};
        *(float2*)&y[(size_t)bid * E_ + c] = o;
    } else if (bid < 3072) {
        int i = ((bid - 2048) * 256 + t) * 4;
        float4 v = *(const float4*)&enc[i];
        encb[i + 0] = __float2bfloat16(v.x);
        encb[i + 1] = __float2bfloat16(v.y);
        encb[i + 2] = __float2bfloat16(v.z);
        encb[i + 3] = __float2bfloat16(v.w);
    } else {
        vmbase[(bid - 3072) * 256 + t] = 0.0f;   // 4096 f32 = vms(2048) + vmc(2048)
    }
}

// ---------------- fused: 16x E_xE_ transpose+convert + BigBird masks ----------------
struct TP16 { const float* s[16]; bf16* d[16]; };
__global__ __launch_bounds__(256)
void tconv16m_kernel(TP16 p, unsigned char* masks) {
    __shared__ float Ts[32][33];
    __shared__ unsigned int mto[4][MT_N];
    __shared__ unsigned int mtn[4][MT_N];
    const int z = blockIdx.z;
    if (z == 16) {
        if (blockIdx.x != 0 || blockIdx.y != 0) return;
        const int w = threadIdx.x >> 6, lane = threadIdx.x & 63;
        const unsigned int seeds[4] = {1000u, 1001u, 0u, 1u};
        unsigned char* m = masks + w * 256;
        for (int idx = lane; idx < 256; idx += 64) {
            int i = idx >> 4, j = idx & 15;
            bool v = (j >= i - 1 && j <= i + 1) || i == 0 || i == 15 || j == 0 || j == 15;
            m[idx] = v ? 1 : 0;
        }
        if (lane == 0) {
            unsigned int s = seeds[w];
            for (int i = 0; i < MT_N; ++i) {
                mto[w][i] = s;
                s = 1812433253u * (s ^ (s >> 30)) + (unsigned int)(i + 1);
            }
        }
        __syncthreads();
        for (int i = lane; i < MT_N - MT_M; i += 64) {
            unsigned int y = (mto[w][i] & MT_UP) | (mto[w][i + 1] & MT_LOW);
            mtn[w][i] = mto[w][i + MT_M] ^ (y >> 1) ^ ((y & 1u) ? MT_MAT : 0u);
        }
        __syncthreads();
        for (int i = 227 + lane; i < 454; i += 64) {
            unsigned int y = (mto[w][i] & MT_UP) | (mto[w][i + 1] & MT_LOW);
            mtn[w][i] = mtn[w][i - 227] ^ (y >> 1) ^ ((y & 1u) ? MT_MAT : 0u);
        }
        __syncthreads();
        for (int i = 454 + lane; i < MT_N - 1; i += 64) {
            unsigned int y = (mto[w][i] & MT_UP) | (mto[w][i + 1] & MT_LOW);
            mtn[w][i] = mtn[w][i - 227] ^ (y >> 1) ^ ((y & 1u) ? MT_MAT : 0u);
        }
        __syncthreads();
        if (lane == 0) {
            unsigned int y = (mto[w][MT_N - 1] & MT_UP) | (mtn[w][0] & MT_LOW);
            mtn[w][MT_N - 1] = mtn[w][MT_M - 1] ^ (y >> 1) ^ ((y & 1u) ? MT_MAT : 0u);
        }
        __syncthreads();
        if (lane == 0) {
            int idx = 0;
            for (int i = 0; i < 16; ++i) {
                unsigned long long arr = 0xFEDCBA9876543210ULL;
                for (int k = 15; k > 0; --k) {
                    unsigned int mask = k;
                    mask |= mask >> 1; mask |= mask >> 2; mask |= mask >> 4;
                    unsigned int j;
                    for (;;) {
                        if (idx >= MT_N) {
                            int i2 = 0;
                            for (; i2 < MT_N - MT_M; ++i2) {
                                unsigned int y2 = (mtn[w][i2] & MT_UP) | (mtn[w][i2 + 1] & MT_LOW);
                                mtn[w][i2] = mtn[w][i2 + MT_M] ^ (y2 >> 1) ^ ((y2 & 1u) ? MT_MAT : 0u);
                            }
                            for (; i2 < MT_N - 1; ++i2) {
                                unsigned int y2 = (mtn[w][i2] & MT_UP) | (mtn[w][i2 + 1] & MT_LOW);
                                mtn[w][i2] = mtn[w][i2 - 227] ^ (y2 >> 1) ^ ((y2 & 1u) ? MT_MAT : 0u);
                            }
                            unsigned int y2 = (mtn[w][MT_N - 1] & MT_UP) | (mtn[w][0] & MT_LOW);
                            mtn[w][MT_N - 1] = mtn[w][MT_M - 1] ^ (y2 >> 1) ^ ((y2 & 1u) ? MT_MAT : 0u);
                            idx = 0;
                        }
                        j = mt_temper(mtn[w][idx++]) & mask;
                        if (j <= (unsigned int)k) break;
                    }
                    unsigned int a = (unsigned int)(arr >> (4 * k)) & 15u;
                    unsigned int bnib = (unsigned int)(arr >> (4 * j)) & 15u;
                    arr &= ~((15ULL << (4 * k)) | (15ULL << (4 * j)));
                    arr |= ((unsigned long long)a << (4 * j)) | ((unsigned long long)bnib << (4 * k));
                }
                m[i * 16 + ((arr >> 0) & 15)] = 1;
                m[i * 16 + ((arr >> 4) & 15)] = 1;
                m[i * 16 + ((arr >> 8) & 15)] = 1;
            }
        }
        return;
    }
    const float* W = p.s[z];
    bf16* Wt = p.d[z];
    int k0 = blockIdx.x * 32, n0 = blockIdx.y * 32;
    int lx = threadIdx.x & 31, ly = threadIdx.x >> 5;
    for (int r = ly; r < 32; r += 8)
        Ts[r][lx] = W[(size_t)(k0 + r) * E_ + n0 + lx];
    __syncthreads();
    for (int r = ly; r < 32; r += 8)
        Wt[(size_t)(n0 + r) * E_ + k0 + lx] = __float2bfloat16(Ts[lx][r]);
}

// ---------------- mlp w1 + w2 transpose+convert (one launch) ----------------
__global__ __launch_bounds__(256)
void tconv_mlp_kernel(const float* __restrict__ w1, const float* __restrict__ w2,
                      bf16* __restrict__ w1t, bf16* __restrict__ w2t) {
    __shared__ float Ts[32][33];
    int z = blockIdx.z;
    const float* W; bf16* Wt; int K, N, k0, n0;
    if (z < 2) {
        W = w1 + (size_t)z * E_ * M_; Wt = w1t + (size_t)z * E_ * M_;
        K = E_; N = M_; k0 = blockIdx.y * 32; n0 = blockIdx.x * 32;
    } else {
        W = w2 + (size_t)(z - 2) * M_ * E_; Wt = w2t + (size_t)(z - 2) * M_ * E_;
        K = M_; N = E_; k0 = blockIdx.x * 32; n0 = blockIdx.y * 32;
    }
    int lx = threadIdx.x & 31, ly = threadIdx.x >> 5;
    for (int r = ly; r < 32; r += 8)
        Ts[r][lx] = W[(size_t)(k0 + r) * N + n0 + lx];
    __syncthreads();
    for (int r = ly; r < 32; r += 8)
        Wt[(size_t)(n0 + r) * K + k0 + lx] = __float2bfloat16(Ts[lx][r]);
}

// ---------------- generic transpose+convert (logits weight) ----------------
__global__ __launch_bounds__(256)
void tconv_kernel(const float* __restrict__ W, bf16* __restrict__ Wt, int K, int N) {
    __shared__ float Ts[32][33];
    int k0 = blockIdx.x * 32, n0 = blockIdx.y * 32;
    int lx = threadIdx.x & 31, ly = threadIdx.x >> 5;
    for (int r = ly; r < 32; r += 8)
        Ts[r][lx] = W[(size_t)(k0 + r) * N + n0 + lx];
    __syncthreads();
    for (int r = ly; r < 32; r += 8)
        Wt[(size_t)(n0 + r) * K + k0 + lx] = __float2bfloat16(Ts[lx][r]);
}

// ---------------- layernorm f32 -> bf16 ----------------
__global__ __launch_bounds__(256)
void ln_kernel(const float* __restrict__ x, bf16* __restrict__ y,
               const float* __restrict__ sc, const float* __restrict__ bi) {
    int row = blockIdx.x;
    int t = threadIdx.x;
    const float* xr = x + (size_t)row * E_;
    float2 v = *(const float2*)&xr[t * 2];
    float sum = v.x + v.y;
    float sq = v.x * v.x + v.y * v.y;
    for (int off = 32; off > 0; off >>= 1) {
        sum += __shfl_xor(sum, off);
        sq  += __shfl_xor(sq, off);
    }
    __shared__ float s0[4], s1[4];
    int w = t >> 6;
    if ((t & 63) == 0) { s0[w] = sum; s1[w] = sq; }
    __syncthreads();
    sum = s0[0] + s0[1] + s0[2] + s0[3];
    sq  = s1[0] + s1[1] + s1[2] + s1[3];
    float mu = sum * (1.0f / (float)E_);
    float var = sq * (1.0f / (float)E_) - mu * mu;
    float rs = rsqrtf(var + 1e-6f);
    float2 s2 = *(const float2*)&sc[t * 2];
    float2 b2 = *(const float2*)&bi[t * 2];
    bf16* yr = y + (size_t)row * E_ + t * 2;
    yr[0] = __float2bfloat16((v.x - mu) * rs * s2.x + b2.x);
    yr[1] = __float2bfloat16((v.y - mu) * rs * s2.y + b2.y);
}

// ---------------- bf16 MFMA GEMM (m97 structure, XCD-swizzled) ----------------
// FM = per-wave M fragments (BM = FM*32). FN = per-wave N fragments (BN = FN*32).
// VS = fuse column-sum of bf16-rounded V-range outputs into vsum (atomics).
// Swapped-operand MFMA -> vectorized float4/uint2 epilogue.
template<int OBF, int FM, int VS, int FN = 4>
__global__ __launch_bounds__(256)
void gemm_mfma(const bf16* __restrict__ A, const bf16* __restrict__ Wt,
               const float* __restrict__ bias, const float* __restrict__ resid,
               void* __restrict__ Cv, int M, int N, int K, float alpha, int relu,
               float* __restrict__ vsum, int vlo)
{
    constexpr int BN = FN * 32;
    __shared__ bf16 As[FM * 32 * 64];
    __shared__ bf16 Bs[BN * 64];
    const int t = threadIdx.x;
    const int lane = t & 63, w = t >> 6;
    int m0, n0;
    {
        int nwg = gridDim.x * gridDim.y;
        int lin = blockIdx.x + gridDim.x * blockIdx.y;
        int q = nwg >> 3, r = nwg & 7;
        int xcd = lin & 7, off8 = lin >> 3;
        int swz = ((xcd < r) ? xcd * (q + 1) : r * (q + 1) + (xcd - r) * q) + off8;
        int gridM = gridDim.y;
        m0 = (swz % gridM) * (FM * 32);
        n0 = (swz / gridM) * BN;
    }
    const int wr = w >> 1, wc = w & 1;
    const int srow = w * 8 + (lane >> 3);
    const int sslot = lane & 7;
    f32x4 acc[FM][FN] = {};

    for (int k0 = 0; k0 < K; k0 += 64) {
        __syncthreads();
        #pragma unroll
        for (int i = 0; i < FM; ++i) {
            int r = i * 32 + srow;
            int gslot = sslot ^ (r & 7);
            const bf16* ga = A + (size_t)(m0 + r) * K + k0 + gslot * 8;
            __builtin_amdgcn_global_load_lds((const __attribute__((address_space(1))) void*)ga,
                                             (__attribute__((address_space(3))) void*)&As[r * 64 + sslot * 8],
                                             16, 0, 0);
        }
        #pragma unroll
        for (int i = 0; i < FN; ++i) {
            int r = i * 32 + srow;
            int gslot = sslot ^ (r & 7);
            const bf16* gb = Wt + (size_t)(n0 + r) * K + k0 + gslot * 8;
            __builtin_amdgcn_global_load_lds((const __attribute__((address_space(1))) void*)gb,
                                             (__attribute__((address_space(3))) void*)&Bs[r * 64 + sslot * 8],
                                             16, 0, 0);
        }
        __syncthreads();
        #pragma unroll
        for (int kk = 0; kk < 2; ++kk) {
            short8 af[FM], bq[FN];
            const int q = kk * 4 + (lane >> 4);
            #pragma unroll
            for (int m = 0; m < FM; ++m) {
                int r = wr * (FM * 16) + m * 16 + (lane & 15);
                af[m] = *(const short8*)&As[r * 64 + (q ^ (r & 7)) * 8];
            }
            #pragma unroll
            for (int n = 0; n < FN; ++n) {
                int r = wc * (FN * 16) + n * 16 + (lane & 15);
                bq[n] = *(const short8*)&Bs[r * 64 + (q ^ (r & 7)) * 8];
            }
            #pragma unroll
            for (int m = 0; m < FM; ++m)
                #pragma unroll
                for (int n = 0; n < FN; ++n)
                    acc[m][n] = __builtin_amdgcn_mfma_f32_16x16x32_bf16(bq[n], af[m], acc[m][n], 0, 0, 0);
        }
    }

    const int lr = lane >> 4, lc = lane & 15;
    float vpart[FN][4] = {};
    #pragma unroll
    for (int m = 0; m < FM; ++m) {
        int row = m0 + wr * (FM * 16) + m * 16 + lc;
        #pragma unroll
        for (int n = 0; n < FN; ++n) {
            int colb = n0 + wc * (FN * 16) + n * 16 + lr * 4;
            float v0 = acc[m][n][0] * alpha, v1 = acc[m][n][1] * alpha;
            float v2 = acc[m][n][2] * alpha, v3 = acc[m][n][3] * alpha;
            if (bias) {
                float4 bv = *(const float4*)&bias[colb];
                v0 += bv.x; v1 += bv.y; v2 += bv.z; v3 += bv.w;
            }
            if (relu) {
                v0 = fmaxf(v0, 0.0f); v1 = fmaxf(v1, 0.0f);
                v2 = fmaxf(v2, 0.0f); v3 = fmaxf(v3, 0.0f);
            }
            if (resid) {
                float4 rv = *(const float4*)&resid[(size_t)row * N + colb];
                v0 += rv.x; v1 += rv.y; v2 += rv.z; v3 += rv.w;
            }
            if (OBF) {
                uint2 pp = {pack2bf(v0, v1), pack2bf(v2, v3)};
                *(uint2*)((bf16*)Cv + (size_t)row * N + colb) = pp;
                if constexpr (VS) {
                    vpart[n][0] += __uint_as_float(pp.x << 16);
                    vpart[n][1] += __uint_as_float(pp.x & 0xffff0000u);
                    vpart[n][2] += __uint_as_float(pp.y << 16);
                    vpart[n][3] += __uint_as_float(pp.y & 0xffff0000u);
                }
            } else {
                float4 o = {v0, v1, v2, v3};
                *(float4*)((float*)Cv + (size_t)row * N + colb) = o;
            }
        }
    }
    if constexpr (VS) {
        int bidx = (m0 + wr * (FM * 16)) >> 10;
        #pragma unroll
        for (int n = 0; n < FN; ++n) {
            #pragma unroll
            for (int j = 0; j < 4; ++j) {
                float s = vpart[n][j];
                s += __shfl_xor(s, 1); s += __shfl_xor(s, 2);
                s += __shfl_xor(s, 4); s += __shfl_xor(s, 8);
                vpart[n][j] = s;
            }
            if (lc == 0) {
                int colb = n0 + wc * (FN * 16) + n * 16 + lr * 4;
                int rr = colb - vlo;
                if (rr >= 0) {
                    int g = rr >> 10, d = rr & 1023;
                    if (d < 512) {
                        float* dst = vsum + g * (B_ * 512) + bidx * 512 + d;
                        atomicAdd(dst + 0, vpart[n][0]);
                        atomicAdd(dst + 1, vpart[n][1]);
                        atomicAdd(dst + 2, vpart[n][2]);
                        atomicAdd(dst + 3, vpart[n][3]);
                    }
                }
            }
        }
    }
}

// ---------------- MFMA flash attention ----------------
__global__ __launch_bounds__(128)
void attn_mfma(const bf16* __restrict__ qp, const bf16* __restrict__ kp,
               const bf16* __restrict__ vp, bf16* __restrict__ op,
               const unsigned char* __restrict__ bm,
               const int* __restrict__ targets, const float* __restrict__ srcmask,
               const float* __restrict__ vmean,
               int sq, int sk, int sv, int causal)
{
    __shared__ __align__(16) unsigned char lds[24592];
    unsigned long long* padb = (unsigned long long*)(lds + 24576);

    const int bid = blockIdx.x;
    const int qb = bid & 15, h = (bid >> 4) & 7, b = bid >> 7;
    const int tid = threadIdx.x;
    const int wq = tid >> 6, lane = tid & 63;
    const int h5 = lane >> 5, l31 = lane & 31;

    unsigned char* Ks = lds;
    unsigned char* Vt = lds + 8192;
    unsigned char* Qs = lds + 16384;

    #pragma unroll
    for (int j = 0; j < 4; ++j) {
        int r = wq * 32 + j * 8 + (lane >> 3);
        int g = (lane & 7) ^ (r & 7);
        const bf16* src = qp + (size_t)(b * S_ + qb * 64 + r) * sq + h * 64 + g * 8;
        __builtin_amdgcn_global_load_lds((const __attribute__((address_space(1))) void*)src,
            (__attribute__((address_space(3))) void*)(Qs + wq * 4096 + j * 1024 + lane * 16),
            16, 0, 0);
    }
    __syncthreads();
    short8 qfrag[4];
    {
        int qrow = wq * 32 + l31;
        #pragma unroll
        for (int t = 0; t < 4; ++t) {
            int c = (2 * t + h5) ^ (qrow & 7);
            qfrag[t] = *(const short8*)(Qs + qrow * 128 + c * 16);
        }
    }

    const int q_in = wq * 32 + l31;
    const int qg = qb * 64 + q_in;
    const bool padq = targets[b * S_ + qg] > 0;

    unsigned long long lstpk = 0ULL;
    int myn = 0;
    {
        int kbmax = causal ? qb : 15;
        for (int kb = 0; kb <= kbmax; ++kb)
            if (bm[qb * 16 + kb]) { lstpk |= ((unsigned long long)kb) << (4 * myn); ++myn; }
    }

    float mrun = -3.0e38f, lrun = 0.0f;
    f32x16 acc0 = {}, acc1 = {};

    for (int it = 0; it < myn; ++it) {
        int kb = (int)((lstpk >> (4 * it)) & 15ULL);
        #pragma unroll
        for (int j = 0; j < 4; ++j) {
            int r = j * 16 + wq * 8 + (lane >> 3);
            int g = (lane & 7) ^ (r & 7);
            const bf16* src = kp + (size_t)(b * S_ + kb * 64 + r) * sk + h * 64 + g * 8;
            __builtin_amdgcn_global_load_lds((const __attribute__((address_space(1))) void*)src,
                (__attribute__((address_space(3))) void*)(Ks + (j * 16 + wq * 8) * 128 + lane * 16),
                16, 0, 0);
        }
        #pragma unroll
        for (int itv = 0; itv < 2; ++itv) {
            int k2 = 2 * l31;
            int d0 = h5 * 8 + (wq * 2 + itv) * 16;
            const unsigned short* v0 = (const unsigned short*)vp +
                (size_t)(b * S_ + kb * 64 + k2) * sv + h * 64 + d0;
            short8 va = *(const short8*)v0;
            short8 vb = *(const short8*)(v0 + sv);
            #pragma unroll
            for (int j2 = 0; j2 < 8; ++j2) {
                int d = d0 + j2;
                unsigned int pkv = ((unsigned int)(unsigned short)va[j2]) |
                                   (((unsigned int)(unsigned short)vb[j2]) << 16);
                int off = d * 128 + (((k2 >> 3) ^ (d & 7)) * 16) + (k2 & 7) * 2;
                *(unsigned int*)(Vt + off) = pkv;
            }
        }
        if (wq == 0) {
            int pos = b * S_ + kb * 64 + lane;
            bool pk_ = srcmask ? (srcmask[pos] > 0.0f) : (targets[pos] > 0);
            unsigned long long bits = __ballot(pk_);
            if (lane == 0) padb[0] = bits;
        }
        __syncthreads();
        {
            bool diag = causal && (kb == qb);
            unsigned long long pb = padb[0];
            #pragma unroll
            for (int ks = 0; ks < 2; ++ks) {
                f32x16 sacc = {};
                #pragma unroll
                for (int t = 0; t < 4; ++t) {
                    int row = ks * 32 + l31;
                    int c = (2 * t + h5) ^ (row & 7);
                    short8 kfrag = *(const short8*)(Ks + row * 128 + c * 16);
                    sacc = __builtin_amdgcn_mfma_f32_32x32x16_bf16(kfrag, qfrag[t], sacc, 0, 0, 0);
                }
                float p[16];
                float mloc = -3.0e38f;
                #pragma unroll
                for (int r = 0; r < 16; ++r) {
                    int kl = ks * 32 + (r & 3) + 8 * (r >> 2) + 4 * h5;
                    bool ok = padq && (((pb >> kl) & 1ULL) != 0) && (!diag || kl <= q_in);
                    p[r] = ok ? sacc[r] * 0.125f : -1.0e9f;
                    mloc = fmaxf(mloc, p[r]);
                }
                mloc = fmaxf(mloc, __shfl_xor(mloc, 32));
                float mnew = fmaxf(mrun, mloc);
                float rescale = __expf(mrun - mnew);
                float lsum = 0.0f;
                #pragma unroll
                for (int r = 0; r < 16; ++r) { p[r] = __expf(p[r] - mnew); lsum += p[r]; }
                lsum += __shfl_xor(lsum, 32);
                lrun = lrun * rescale + lsum;
                mrun = mnew;
                acc0 *= rescale;
                acc1 *= rescale;
                unsigned int pk_hi[4][2], pk_lo[4][2];
                #pragma unroll
                for (int t4 = 0; t4 < 4; ++t4)
                    #pragma unroll
                    for (int u = 0; u < 2; ++u) {
                        float a = p[4 * t4 + 2 * u];
                        float c = p[4 * t4 + 2 * u + 1];
                        unsigned int ph = pack2bf(a, c);
                        float ah = __uint_as_float(ph << 16);
                        float ch = __uint_as_float(ph & 0xffff0000u);
                        pk_hi[t4][u] = ph;
                        pk_lo[t4][u] = pack2bf(a - ah, c - ch);
                    }
                #pragma unroll
                for (int Hh = 0; Hh < 2; ++Hh) {
                    unsigned int hu0 = (unsigned int)__shfl_xor((int)pk_hi[2 * Hh + 1][0], 32);
                    unsigned int hu1 = (unsigned int)__shfl_xor((int)pk_hi[2 * Hh + 1][1], 32);
                    unsigned int hl0 = (unsigned int)__shfl_xor((int)pk_hi[2 * Hh][0], 32);
                    unsigned int hl1 = (unsigned int)__shfl_xor((int)pk_hi[2 * Hh][1], 32);
                    uint4v hv = {h5 ? hu0 : pk_hi[2 * Hh][0],
                                 h5 ? hu1 : pk_hi[2 * Hh][1],
                                 h5 ? pk_hi[2 * Hh + 1][0] : hl0,
                                 h5 ? pk_hi[2 * Hh + 1][1] : hl1};
                    short8 bfrag_hi = __builtin_bit_cast(short8, hv);
                    unsigned int lu0 = (unsigned int)__shfl_xor((int)pk_lo[2 * Hh + 1][0], 32);
                    unsigned int lu1 = (unsigned int)__shfl_xor((int)pk_lo[2 * Hh + 1][1], 32);
                    unsigned int ll0 = (unsigned int)__shfl_xor((int)pk_lo[2 * Hh][0], 32);
                    unsigned int ll1 = (unsigned int)__shfl_xor((int)pk_lo[2 * Hh][1], 32);
                    uint4v lv = {h5 ? lu0 : pk_lo[2 * Hh][0],
                                 h5 ? lu1 : pk_lo[2 * Hh][1],
                                 h5 ? pk_lo[2 * Hh + 1][0] : ll0,
                                 h5 ? pk_lo[2 * Hh + 1][1] : ll1};
                    short8 bfrag_lo = __builtin_bit_cast(short8, lv);
                    #pragma unroll
                    for (int f = 0; f < 2; ++f) {
                        int row = f * 32 + l31;
                        int c = (4 * ks + 2 * Hh + h5) ^ (row & 7);
                        short8 vfrag = *(const short8*)(Vt + row * 128 + c * 16);
                        if (f == 0) {
                            acc0 = __builtin_amdgcn_mfma_f32_32x32x16_bf16(vfrag, bfrag_hi, acc0, 0, 0, 0);
                            acc0 = __builtin_amdgcn_mfma_f32_32x32x16_bf16(vfrag, bfrag_lo, acc0, 0, 0, 0);
                        } else {
                            acc1 = __builtin_amdgcn_mfma_f32_32x32x16_bf16(vfrag, bfrag_hi, acc1, 0, 0, 0);
                            acc1 = __builtin_amdgcn_mfma_f32_32x32x16_bf16(vfrag, bfrag_lo, acc1, 0, 0, 0);
                        }
                    }
                }
            }
        }
        __syncthreads();
    }

    bool okrow = mrun > -5.0e8f;
    float inv = okrow ? 1.0f / lrun : 0.0f;
    const float* vmp = vmean + (b * 8 + h) * 64;
    const float invS = 1.0f / (float)S_;
    unsigned short* orow = (unsigned short*)op + (size_t)(b * S_ + qg) * E_ + h * 64;
    #pragma unroll
    for (int f = 0; f < 2; ++f)
        #pragma unroll
        for (int t4 = 0; t4 < 4; ++t4)
            #pragma unroll
            for (int u = 0; u < 2; ++u) {
                int r = 4 * t4 + 2 * u;
                int d = f * 32 + 2 * u + 8 * t4 + 4 * h5;
                float a0 = f ? acc1[r] : acc0[r];
                float a1 = f ? acc1[r + 1] : acc0[r + 1];
                float v0 = a0 * inv;
                float v1 = a1 * inv;
                if (!okrow) { v0 = vmp[d] * invS; v1 = vmp[d + 1] * invS; }
                *(unsigned int*)(orow + d) = pack2bf(v0, v1);
            }
}

extern "C" void kernel_launch(void* const* d_in, const int* in_sizes, int n_in,
                              void* d_out, int out_size, void* d_ws, size_t ws_size,
                              hipStream_t stream)
{
    const float* encoded  = (const float*)d_in[0];
    const float* srcmask  = (const float*)d_in[1];
    const int*   targets  = (const int*)d_in[2];
    const float* table    = (const float*)d_in[3];
    const float* pos      = (const float*)d_in[4];
    const float* ln1_s = (const float*)d_in[5];
    const float* ln1_b = (const float*)d_in[6];
    const float* ln2_s = (const float*)d_in[7];
    const float* ln2_b = (const float*)d_in[8];
    const float* ln3_s = (const float*)d_in[9];
    const float* ln3_b = (const float*)d_in[10];
    const float* self_wq = (const float*)d_in[11];
    const float* self_wk = (const float*)d_in[12];
    const float* self_wv = (const float*)d_in[13];
    const float* self_wo = (const float*)d_in[14];
    const float* cross_wq = (const float*)d_in[15];
    const float* cross_wk = (const float*)d_in[16];
    const float* cross_wv = (const float*)d_in[17];
    const float* cross_wo = (const float*)d_in[18];
    const float* mlp_w1 = (const float*)d_in[19];
    const float* mlp_b1 = (const float*)d_in[20];
    const float* mlp_w2 = (const float*)d_in[21];
    const float* mlp_b2 = (const float*)d_in[22];
    const float* final_s = (const float*)d_in[23];
    const float* final_b = (const float*)d_in[24];
    const float* logit_w = (const float*)d_in[25];
    const float* logit_b = (const float*)d_in[26];
    float* out = (float*)d_out;

    char* ws = (char*)d_ws;
    unsigned char* masks = (unsigned char*)ws;
    size_t off = 1024;
    auto alloc = [&](size_t bytes) {
        char* p = ws + off;
        off += (bytes + 255) & ~(size_t)255;
        return p;
    };
    const size_t RS = (size_t)B_ * S_;   // 2048
    const size_t EE = (size_t)E_ * E_;
    float* y    = (float*)alloc(RS * E_ * 4);
    float* xb   = (float*)alloc(RS * E_ * 4);
    float* zb   = (float*)alloc(RS * E_ * 4);
    bf16* lnb   = (bf16*)alloc(RS * E_ * 2);
    bf16* qkvb  = (bf16*)alloc(RS * 3 * E_ * 2);
    bf16* kvb   = (bf16*)alloc(RS * 4 * E_ * 2);   // [k0|v0|k1|v1] per row
    bf16* qb2   = (bf16*)alloc(RS * E_ * 2);
    bf16* ob    = (bf16*)alloc(RS * E_ * 2);
    bf16* hid   = (bf16*)alloc(RS * M_ * 2);
    bf16* encb  = (bf16*)alloc(RS * E_ * 2);
    float* vmbase = (float*)alloc(4096 * 4);       // vms[2][B][512] + vmc[2][B][512]
    float* vms = vmbase;
    float* vmc = vmbase + 2048;
    bf16* qkv_t = (bf16*)alloc((size_t)L_ * 3 * EE * 2);
    bf16* swo_t = (bf16*)alloc((size_t)L_ * EE * 2);
    bf16* cq_t  = (bf16*)alloc((size_t)L_ * EE * 2);
    bf16* ckv_t = (bf16*)alloc((size_t)L_ * 2 * EE * 2);
    bf16* cwo_t = (bf16*)alloc((size_t)L_ * EE * 2);
    bf16* w1_t  = (bf16*)alloc((size_t)L_ * E_ * M_ * 2);
    bf16* w2_t  = (bf16*)alloc((size_t)L_ * M_ * E_ * 2);
    bf16* wl_t  = (bf16*)alloc((size_t)E_ * V_ * 2);

    const int R = (int)RS;

    prep_kernel<<<3088, 256, 0, stream>>>(targets, table, pos, y, encoded, encb, vmbase);

    {
        TP16 p;
        for (int l = 0; l < L_; ++l) {
            p.s[l * 8 + 0] = self_wq + l * EE;  p.d[l * 8 + 0] = qkv_t + (size_t)l * 3 * EE + 0 * EE;
            p.s[l * 8 + 1] = self_wk + l * EE;  p.d[l * 8 + 1] = qkv_t + (size_t)l * 3 * EE + 1 * EE;
            p.s[l * 8 + 2] = self_wv + l * EE;  p.d[l * 8 + 2] = qkv_t + (size_t)l * 3 * EE + 2 * EE;
            p.s[l * 8 + 3] = self_wo + l * EE;  p.d[l * 8 + 3] = swo_t + (size_t)l * EE;
            p.s[l * 8 + 4] = cross_wq + l * EE; p.d[l * 8 + 4] = cq_t + (size_t)l * EE;
            p.s[l * 8 + 5] = cross_wk + l * EE; p.d[l * 8 + 5] = ckv_t + (size_t)l * 2 * EE + 0 * EE;
            p.s[l * 8 + 6] = cross_wv + l * EE; p.d[l * 8 + 6] = ckv_t + (size_t)l * 2 * EE + 1 * EE;
            p.s[l * 8 + 7] = cross_wo + l * EE; p.d[l * 8 + 7] = cwo_t + (size_t)l * EE;
        }
        dim3 gf(E_ / 32, E_ / 32, 17);
        tconv16m_kernel<<<gf, 256, 0, stream>>>(p, masks);
        dim3 gm(64, 16, 4);
        tconv_mlp_kernel<<<gm, 256, 0, stream>>>(mlp_w1, mlp_w2, w1_t, w2_t);
        dim3 g3(E_ / 32, V_ / 32, 1);
        tconv_kernel<<<g3, 256, 0, stream>>>(logit_w, wl_t, E_, V_);
    }

    dim3 gqkv2(3 * E_ / 128, R / 64);    // 12 x 32 = 384 WGs
    dim3 gkv42(4 * E_ / 128, R / 64);    // 16 x 32 = 512 WGs
    dim3 gp2(E_ / 128, R / 64);          // 4 x 32 = 128 WGs
    dim3 g12(M_ / 128, R / 64);          // 16 x 32 = 512 WGs
    dim3 gl8(V_ / 256, R / 64);          // 125 x 32 = 4000 WGs (FN=8, BN=256)
    const int attn_grid = B_ * H_ * 16;

    // cross K/V for BOTH layers upfront, vmeans fused via atomics
    gemm_mfma<1, 2, 1><<<gkv42, 256, 0, stream>>>(encb, ckv_t, nullptr, nullptr, kvb, R, 4 * E_, E_, 1.0f, 0, vmc, 512);

    for (int l = 0; l < L_; ++l) {
        // ---- self attention ----
        ln_kernel<<<R, 256, 0, stream>>>(y, lnb, ln1_s + l * E_, ln1_b + l * E_);
        gemm_mfma<1, 2, 1><<<gqkv2, 256, 0, stream>>>(lnb, qkv_t + (size_t)l * 3 * EE, nullptr, nullptr, qkvb, R, 3 * E_, E_, 1.0f, 0, vms + l * (B_ * 512), 1024);
        attn_mfma<<<attn_grid, 128, 0, stream>>>(qkvb, qkvb + E_, qkvb + 2 * E_, ob, masks + l * 256,
                                                 targets, nullptr, vms + l * (B_ * 512), 3 * E_, 3 * E_, 3 * E_, 1);
        gemm_mfma<0, 2, 0><<<gp2, 256, 0, stream>>>(ob, swo_t + (size_t)l * EE, nullptr, y, xb, R, E_, E_, 1.0f, 0, nullptr, 0);
        // ---- cross attention ----
        ln_kernel<<<R, 256, 0, stream>>>(xb, lnb, ln2_s + l * E_, ln2_b + l * E_);
        gemm_mfma<1, 2, 0><<<gp2, 256, 0, stream>>>(lnb, cq_t + (size_t)l * EE, nullptr, nullptr, qb2, R, E_, E_, 1.0f, 0, nullptr, 0);
        attn_mfma<<<attn_grid, 128, 0, stream>>>(qb2, kvb + (size_t)l * 2 * E_, kvb + (size_t)l * 2 * E_ + E_, ob,
                                                 masks + (2 + l) * 256, targets, srcmask,
                                                 vmc + l * (B_ * 512), E_, 4 * E_, 4 * E_, 0);
        gemm_mfma<0, 2, 0><<<gp2, 256, 0, stream>>>(ob, cwo_t + (size_t)l * EE, nullptr, xb, zb, R, E_, E_, 1.0f, 0, nullptr, 0);
        // ---- MLP ----
        ln_kernel<<<R, 256, 0, stream>>>(zb, lnb, ln3_s + l * E_, ln3_b + l * E_);
        gemm_mfma<1, 2, 0><<<g12, 256, 0, stream>>>(lnb, w1_t + (size_t)l * E_ * M_, mlp_b1 + (size_t)l * M_, nullptr, hid, R, M_, E_, 1.0f, 1, nullptr, 0);
        gemm_mfma<0, 2, 0><<<gp2, 256, 0, stream>>>(hid, w2_t + (size_t)l * M_ * E_, mlp_b2 + (size_t)l * E_, zb, y, R, E_, M_, 1.0f, 0, nullptr, 0);
    }

    ln_kernel<<<R, 256, 0, stream>>>(y, lnb, final_s, final_b);
    gemm_mfma<0, 2, 0, 8><<<gl8, 256, 0, stream>>>(lnb, wl_t, logit_b, nullptr, out, R, V_, E_, 1.0f, 0, nullptr, 0);
}